// Round 4
// baseline (3109.947 us; speedup 1.0000x reference)
//
#include <hip/hip_runtime.h>
#include <float.h>
#include <math.h>
#include <stdint.h>

// Problem constants (match reference)
constexpr int B   = 8;
constexpr int C   = 96;
constexpr int N   = 3136;   // 56*56
constexpr int M   = 784;    // RATIO*N
constexpr int C4  = 384;    // 4*C
constexpr int OUT = 192;
constexpr int KD  = 16;     // K_DPC
constexpr int TK  = 5;      // TOPK

// ---------------------------------------------------------------------------
// fp32 round-to-nearest of a positive double WITH flush-to-zero of subnormal
// results (GPU v_exp_f32 / FTZ-process semantics). Returns order-preserving
// uint32 bit pattern (0 for flushed).
__device__ inline uint32_t f32q_ftz(double t) {
    if (t <= 0.0) return 0u;
    float f = (float)t;              // exact RN cvt (double->float)
    if (f < 0x1p-126f) return 0u;    // subnormal result -> flush to zero
    return __float_as_uint(f);
}

// ---------------------------------------------------------------------------
// K0: per-point squared norms of y and x (both laid out (B,C,N))
__global__ __launch_bounds__(256) void k_norms(const float* __restrict__ y,
                                               const float* __restrict__ x,
                                               float* __restrict__ ynorm,
                                               float* __restrict__ xnorm) {
    int id = blockIdx.x * 256 + threadIdx.x;
    if (id >= B * N) return;
    int b = id / N, n = id % N;
    const float* yb = y + (size_t)b * C * N + n;
    const float* xb = x + (size_t)b * C * N + n;
    float sy = 0.f, sx = 0.f;
    #pragma unroll 8
    for (int c = 0; c < C; ++c) {
        float a = yb[(size_t)c * N]; sy += a * a;
        float d = xb[(size_t)c * N]; sx += d * d;
    }
    ynorm[id] = sy;
    xnorm[id] = sx;
}

// ---------------------------------------------------------------------------
// K1: per-row d (fp32), 16-smallest selection (values ascending), numpy-tree
// fp32 mean, density = FTZ-fp32 exp(-mean) as bit pattern. Also row max.
template <bool STORED>
__global__ __launch_bounds__(256) void k_density(const float* __restrict__ y,
                                                 const float* __restrict__ rel,
                                                 const float* __restrict__ ynorm,
                                                 uint32_t* __restrict__ densbits,
                                                 float* __restrict__ rowmax,
                                                 float* __restrict__ dmat) {
    const int i = blockIdx.x;
    const int b = blockIdx.y;
    const int t = threadIdx.x;
    __shared__ float yi[C];
    __shared__ float dist[N];
    __shared__ float rv[256];
    __shared__ int   ri[256];
    __shared__ float selv[KD];

    const float* yb = y + (size_t)b * C * N;
    if (t < C) yi[t] = yb[(size_t)t * N + i];
    __syncthreads();

    const float ni = ynorm[b * N + i];
    float lmax = -FLT_MAX;
    for (int j = t; j < N; j += 256) {
        const float* p = yb + j;
        float dot = 0.f;
        #pragma unroll 8
        for (int c = 0; c < C; ++c) dot += yi[c] * p[(size_t)c * N];
        float d = ni + ynorm[b * N + j] - 2.f * dot + rel[(size_t)i * N + j];
        dist[j] = d;
        if (STORED) dmat[((size_t)b * N + i) * N + j] = d;
        lmax = fmaxf(lmax, d);
    }
    rv[t] = lmax;
    __syncthreads();
    for (int s = 128; s > 0; s >>= 1) {
        if (t < s) rv[t] = fmaxf(rv[t], rv[t + s]);
        __syncthreads();
    }
    if (t == 0) rowmax[b * N + i] = rv[0];
    __syncthreads();

    // select the 16 smallest values of dist[], ascending
    for (int r = 0; r < KD; ++r) {
        float lv = FLT_MAX; int li = 0;
        for (int j = t; j < N; j += 256) {
            float v = dist[j];
            if (v < lv) { lv = v; li = j; }
        }
        rv[t] = lv; ri[t] = li;
        __syncthreads();
        for (int s = 128; s > 0; s >>= 1) {
            if (t < s) {
                if (rv[t + s] < rv[t]) { rv[t] = rv[t + s]; ri[t] = ri[t + s]; }
            }
            __syncthreads();
        }
        if (t == 0) { selv[r] = rv[0]; dist[ri[0]] = FLT_MAX; }
        __syncthreads();
    }

    if (t == 0) {
        // numpy pairwise fp32 sum of 16 (ascending order): r[j]=a[j]+a[8+j],
        // then ((r0+r1)+(r2+r3)) + ((r4+r5)+(r6+r7)); mean = sum/16 (exact)
        float r8[8];
        #pragma unroll
        for (int j2 = 0; j2 < 8; ++j2) r8[j2] = selv[j2] + selv[8 + j2];
        float s = ((r8[0] + r8[1]) + (r8[2] + r8[3]))
                + ((r8[4] + r8[5]) + (r8[6] + r8[7]));
        float mean = s * (1.0f / 16.0f);
        densbits[b * N + i] = f32q_ftz(exp(-(double)mean));
    }
}

// ---------------------------------------------------------------------------
// K2: per-batch global max of d (fp32)
__global__ __launch_bounds__(256) void k_dmax(const float* __restrict__ rowmax,
                                              float* __restrict__ dmax) {
    int b = blockIdx.x, t = threadIdx.x;
    __shared__ float rv[256];
    float lm = -FLT_MAX;
    for (int j = t; j < N; j += 256) lm = fmaxf(lm, rowmax[b * N + j]);
    rv[t] = lm;
    __syncthreads();
    for (int s = 128; s > 0; s >>= 1) {
        if (t < s) rv[t] = fmaxf(rv[t], rv[t + s]);
        __syncthreads();
    }
    if (t == 0) dmax[b] = rv[0];
}

// ---------------------------------------------------------------------------
// K3: dist_peak = min over j with dens[j] > dens[i] of d[i,j] (else dmax);
// score = fp32(dist_peak * density) emulated exactly; packed rank key.
// Zero-density rows short-circuit: score is exactly +0.
template <bool STORED>
__global__ __launch_bounds__(256) void k_score(const float* __restrict__ y,
                                               const float* __restrict__ rel,
                                               const float* __restrict__ ynorm,
                                               const uint32_t* __restrict__ densbits,
                                               const float* __restrict__ dmax,
                                               const float* __restrict__ dmat,
                                               unsigned long long* __restrict__ keys) {
    const int i = blockIdx.x;
    const int b = blockIdx.y;
    const int t = threadIdx.x;

    const uint32_t bi = densbits[b * N + i];
    if (bi == 0u) {   // score == +0.0 exactly; key = (0, ~idx)
        if (t == 0) keys[b * N + i] =
            (unsigned long long)(0xFFFFFFFFu - (uint32_t)i);
        return;
    }

    __shared__ float yi[C];
    __shared__ float rv[256];

    const float* yb = y + (size_t)b * C * N;
    if (!STORED) {
        if (t < C) yi[t] = yb[(size_t)t * N + i];
    }
    __syncthreads();

    const float ni = ynorm[b * N + i];
    float mn = FLT_MAX;
    for (int j = t; j < N; j += 256) {
        if (densbits[b * N + j] > bi) {
            float d;
            if (STORED) {
                d = dmat[((size_t)b * N + i) * N + j];
            } else {
                const float* p = yb + j;
                float dot = 0.f;
                #pragma unroll 8
                for (int c = 0; c < C; ++c) dot += yi[c] * p[(size_t)c * N];
                d = ni + ynorm[b * N + j] - 2.f * dot + rel[(size_t)i * N + j];
            }
            mn = fminf(mn, d);
        }
    }
    rv[t] = mn;
    __syncthreads();
    for (int s = 128; s > 0; s >>= 1) {
        if (t < s) rv[t] = fminf(rv[t], rv[t + s]);
        __syncthreads();
    }
    if (t == 0) {
        float dp = fminf(rv[0], dmax[b]);
        // exact single-rounded fp32 product (both factors are fp32 values)
        double p = (double)dp * (double)__uint_as_float(bi);
        float sf = (float)p;
        uint32_t sb = (sf < 0x1p-126f) ? 0u : __float_as_uint(sf);
        keys[b * N + i] = ((unsigned long long)sb << 32)
                        | (unsigned long long)(0xFFFFFFFFu - (uint32_t)i);
    }
}

// ---------------------------------------------------------------------------
// K4: per-batch bitonic sort of packed keys, descending -> top M indices.
// Key = (score_bits << 32) | ~idx: descending sort == (score desc, idx asc).
__global__ __launch_bounds__(512) void k_topm(const unsigned long long* __restrict__ keys,
                                              int* __restrict__ sidx) {
    constexpr int SZ = 4096;
    int b = blockIdx.x, t = threadIdx.x;
    __shared__ unsigned long long ks[SZ];
    for (int i = t; i < SZ; i += 512) ks[i] = (i < N) ? keys[b * N + i] : 0ull;
    __syncthreads();
    for (int k = 2; k <= SZ; k <<= 1) {
        for (int j = k >> 1; j > 0; j >>= 1) {
            for (int i = t; i < SZ; i += 512) {
                int ixj = i ^ j;
                if (ixj > i) {
                    bool up = ((i & k) == 0);
                    unsigned long long a = ks[i], c2 = ks[ixj];
                    bool doSwap = up ? (a < c2) : (a > c2);  // descending
                    if (doSwap) { ks[i] = c2; ks[ixj] = a; }
                }
            }
            __syncthreads();
        }
    }
    for (int m = t; m < M; m += 512)
        sidx[b * M + m] = (int)(0xFFFFFFFFu - (uint32_t)(ks[m] & 0xFFFFFFFFull));
}

// ---------------------------------------------------------------------------
// K5: gather centers cen[b,m,c] = y[b,c,sidx] and their norms
__global__ __launch_bounds__(128) void k_cen(const float* __restrict__ y,
                                             const int* __restrict__ sidx,
                                             const float* __restrict__ ynorm,
                                             float* __restrict__ cen,
                                             float* __restrict__ cnorm) {
    int m = blockIdx.x, b = blockIdx.y, t = threadIdx.x;
    int j = sidx[b * M + m];
    if (t < C) cen[((size_t)b * M + m) * C + t] = y[((size_t)b * C + t) * N + j];
    if (t == 0) cnorm[b * M + m] = ynorm[b * N + j];
}

// ---------------------------------------------------------------------------
// K6: assignment softmax row + top-5 center indices per point (logit-ranked)
__global__ __launch_bounds__(128) void k_assign(const float* __restrict__ x,
                                                const float* __restrict__ cen,
                                                const float* __restrict__ xnorm,
                                                const float* __restrict__ cnorm,
                                                float* __restrict__ assign,
                                                int* __restrict__ nnidx) {
    const int i = blockIdx.x;
    const int b = blockIdx.y;
    const int t = threadIdx.x;
    __shared__ float xi[C];
    __shared__ float S[M];   // logits
    __shared__ float rv[128];
    __shared__ int   ri[128];

    if (t < C) xi[t] = x[((size_t)b * C + t) * N + i];
    __syncthreads();

    const float xn = xnorm[b * N + i];
    for (int m = t; m < M; m += 128) {
        const float* cm = cen + ((size_t)b * M + m) * C;
        float dot = 0.f;
        #pragma unroll 8
        for (int c = 0; c < C; ++c) dot += xi[c] * cm[c];
        S[m] = -(xn + cnorm[b * M + m] - 2.f * dot);
    }
    __syncthreads();

    float lm = -FLT_MAX;
    for (int m = t; m < M; m += 128) lm = fmaxf(lm, S[m]);
    rv[t] = lm;
    __syncthreads();
    for (int s = 64; s > 0; s >>= 1) {
        if (t < s) rv[t] = fmaxf(rv[t], rv[t + s]);
        __syncthreads();
    }
    float smax = rv[0];
    __syncthreads();

    float lsum = 0.f;
    for (int m = t; m < M; m += 128) lsum += expf(S[m] - smax);
    rv[t] = lsum;
    __syncthreads();
    for (int s = 64; s > 0; s >>= 1) {
        if (t < s) rv[t] += rv[t + s];
        __syncthreads();
    }
    float inv = 1.f / rv[0];
    __syncthreads();

    float* arow = assign + ((size_t)b * N + i) * M;
    for (int m = t; m < M; m += 128) arow[m] = expf(S[m] - smax) * inv;

    for (int r = 0; r < TK; ++r) {
        float lv = -FLT_MAX; int li = M;
        for (int m = t; m < M; m += 128) {
            float v = S[m];
            if (v > lv || (v == lv && m < li)) { lv = v; li = m; }
        }
        rv[t] = lv; ri[t] = li;
        __syncthreads();
        for (int s = 64; s > 0; s >>= 1) {
            if (t < s) {
                if (rv[t + s] > rv[t] || (rv[t + s] == rv[t] && ri[t + s] < ri[t])) {
                    rv[t] = rv[t + s]; ri[t] = ri[t + s];
                }
            }
            __syncthreads();
        }
        if (t == 0) {
            nnidx[((size_t)b * N + i) * TK + r] = ri[0];
            S[ri[0]] = -FLT_MAX;
        }
        __syncthreads();
    }
}

// ---------------------------------------------------------------------------
// K7: agg[b,m,c] = (sum_n assign[n,m] * x[c,n]) / (mass_m + 1e-6)
__global__ __launch_bounds__(256) void k_agg(const float* __restrict__ assign,
                                             const float* __restrict__ x,
                                             float* __restrict__ aggws) {
    const int b = blockIdx.y;
    const int m0 = blockIdx.x * 16;
    const int t = threadIdx.x;
    __shared__ float As[64][16];
    __shared__ float Xs[96][65];
    __shared__ float minv[16];

    float acc[6] = {0.f, 0.f, 0.f, 0.f, 0.f, 0.f};
    float massacc = 0.f;

    for (int n0 = 0; n0 < N; n0 += 64) {
        for (int e = t; e < 64 * 16; e += 256) {
            int nn = e >> 4, mm = e & 15;
            As[nn][mm] = assign[((size_t)b * N + n0 + nn) * M + m0 + mm];
        }
        for (int e = t; e < 96 * 64; e += 256) {
            int c = e >> 6, nn = e & 63;
            Xs[c][nn] = x[((size_t)b * C + c) * N + n0 + nn];
        }
        __syncthreads();
        if (t < 16) {
            #pragma unroll
            for (int nn = 0; nn < 64; ++nn) massacc += As[nn][t];
        }
        #pragma unroll
        for (int u = 0; u < 6; ++u) {
            int e = t + u * 256;
            int mm = e & 15, c = e >> 4;
            float a = acc[u];
            #pragma unroll 8
            for (int nn = 0; nn < 64; ++nn) a += As[nn][mm] * Xs[c][nn];
            acc[u] = a;
        }
        __syncthreads();
    }
    if (t < 16) minv[t] = 1.f / (massacc + 1e-6f);
    __syncthreads();
    #pragma unroll
    for (int u = 0; u < 6; ++u) {
        int e = t + u * 256;
        int mm = e & 15, c = e >> 4;
        aggws[((size_t)b * M + m0 + mm) * C + c] = acc[u] * minv[mm];
    }
}

// ---------------------------------------------------------------------------
// K8: per-center FFN with residual; writes updated agg (ws) and `refined`
__global__ __launch_bounds__(128) void k_ffn(const float* __restrict__ w1,
                                             const float* __restrict__ b1,
                                             const float* __restrict__ g1,
                                             const float* __restrict__ bt1,
                                             const float* __restrict__ w2,
                                             const float* __restrict__ b2,
                                             const float* __restrict__ g2,
                                             const float* __restrict__ bt2,
                                             float* __restrict__ aggws,
                                             float* __restrict__ refined) {
    const int m = blockIdx.x;
    const int b = blockIdx.y;
    const int t = threadIdx.x;
    __shared__ float ar[C];
    __shared__ float hd[C4];

    if (t < C) ar[t] = aggws[((size_t)b * M + m) * C + t];
    __syncthreads();

    for (int o = t; o < C4; o += 128) {
        const float* w = w1 + (size_t)o * C;
        float h = b1[o];
        #pragma unroll 8
        for (int c = 0; c < C; ++c) h += w[c] * ar[c];
        h = h * g1[o] + bt1[o];
        hd[o] = fmaxf(h, 0.f);
    }
    __syncthreads();

    if (t < C) {
        const float* w = w2 + (size_t)t * C4;
        float f = b2[t];
        #pragma unroll 8
        for (int o = 0; o < C4; ++o) f += w[o] * hd[o];
        float v = ar[t] + (f * g2[t] + bt2[t]);
        aggws[((size_t)b * M + m) * C + t] = v;
        refined[((size_t)b * C + t) * M + m] = v;
    }
}

// ---------------------------------------------------------------------------
// K9: rel = max over top-5 agg rows - xf; interleaved xcat;
// out = relu((nn_w @ xcat + nn_b) * g + bt), stored (B, OUT, N)
__global__ __launch_bounds__(256) void k_final(const float* __restrict__ x,
                                               const float* __restrict__ aggws,
                                               const int* __restrict__ nnidx,
                                               const float* __restrict__ nnw,
                                               const float* __restrict__ nnb,
                                               const float* __restrict__ nng,
                                               const float* __restrict__ nnbt,
                                               float* __restrict__ out) {
    const int b = blockIdx.y;
    const int n0 = blockIdx.x * 16;
    const int t = threadIdx.x;
    __shared__ float xc[16][193];
    __shared__ int nid[16 * TK];

    if (t < 16 * TK) nid[t] = nnidx[((size_t)b * N + n0) * TK + t];
    __syncthreads();

    for (int e = t; e < C * 16; e += 256) {
        int c = e >> 4, r = e & 15;
        float xv = x[((size_t)b * C + c) * N + n0 + r];
        float mx = -FLT_MAX;
        #pragma unroll
        for (int k = 0; k < TK; ++k) {
            int j = nid[r * TK + k];
            mx = fmaxf(mx, aggws[((size_t)b * M + j) * C + c]);
        }
        xc[r][2 * c]     = xv;
        xc[r][2 * c + 1] = mx - xv;
    }
    __syncthreads();

    const int r = t & 15;
    const int og = t >> 4;
    #pragma unroll
    for (int oo = 0; oo < 12; ++oo) {
        int o = og + (oo << 4);
        const float* w = nnw + (size_t)o * (2 * C);
        float a = nnb[o];
        #pragma unroll 8
        for (int cc = 0; cc < 2 * C; ++cc) a += w[cc] * xc[r][cc];
        a = a * nng[o] + nnbt[o];
        out[((size_t)b * OUT + o) * N + n0 + r] = fmaxf(a, 0.f);
    }
}

// ---------------------------------------------------------------------------
extern "C" void kernel_launch(void* const* d_in, const int* in_sizes, int n_in,
                              void* d_out, int out_size, void* d_ws, size_t ws_size,
                              hipStream_t stream) {
    const float* x    = (const float*)d_in[0];
    const float* rel  = (const float*)d_in[1];
    const float* y    = (const float*)d_in[2];
    const float* w1   = (const float*)d_in[3];
    const float* b1   = (const float*)d_in[4];
    const float* g1   = (const float*)d_in[5];
    const float* bt1  = (const float*)d_in[6];
    const float* w2   = (const float*)d_in[7];
    const float* b2   = (const float*)d_in[8];
    const float* g2   = (const float*)d_in[9];
    const float* bt2  = (const float*)d_in[10];
    const float* nnw  = (const float*)d_in[11];
    const float* nnb  = (const float*)d_in[12];
    const float* nng  = (const float*)d_in[13];
    const float* nnbt = (const float*)d_in[14];

    float* out     = (float*)d_out;
    float* refined = out + (size_t)B * OUT * N;

    char* w = (char*)d_ws;
    auto alloc = [&](size_t nbytes) -> void* {
        void* p = (void*)w;
        w += (nbytes + 255) & ~(size_t)255;
        return p;
    };
    float*    ynorm    = (float*)   alloc((size_t)B * N * 4);
    float*    xnorm    = (float*)   alloc((size_t)B * N * 4);
    uint32_t* densbits = (uint32_t*)alloc((size_t)B * N * 4);
    float*    rowmax   = (float*)   alloc((size_t)B * N * 4);
    float*    dmaxv    = (float*)   alloc((size_t)B * 4);
    unsigned long long* keys = (unsigned long long*)alloc((size_t)B * N * 8);
    int*      sidx     = (int*)     alloc((size_t)B * M * 4);
    float*    cnorm    = (float*)   alloc((size_t)B * M * 4);
    float*    cen      = (float*)   alloc((size_t)B * M * C * 4);
    float*    aggws    = (float*)   alloc((size_t)B * M * C * 4);
    int*      nnidx    = (int*)     alloc((size_t)B * N * TK * 4);
    float*    assign   = (float*)   alloc((size_t)B * N * M * 4);

    size_t used = (size_t)(w - (char*)d_ws);
    size_t dmat_bytes = (size_t)B * N * N * 4;
    float* dmat = nullptr;
    if (ws_size >= used + dmat_bytes) dmat = (float*)alloc(dmat_bytes);
    const bool stored = (dmat != nullptr);

    k_norms<<<dim3((B * N + 255) / 256), dim3(256), 0, stream>>>(y, x, ynorm, xnorm);

    if (stored)
        k_density<true ><<<dim3(N, B), dim3(256), 0, stream>>>(y, rel, ynorm, densbits, rowmax, dmat);
    else
        k_density<false><<<dim3(N, B), dim3(256), 0, stream>>>(y, rel, ynorm, densbits, rowmax, dmat);

    k_dmax<<<dim3(B), dim3(256), 0, stream>>>(rowmax, dmaxv);

    if (stored)
        k_score<true ><<<dim3(N, B), dim3(256), 0, stream>>>(y, rel, ynorm, densbits, dmaxv, dmat, keys);
    else
        k_score<false><<<dim3(N, B), dim3(256), 0, stream>>>(y, rel, ynorm, densbits, dmaxv, dmat, keys);

    k_topm<<<dim3(B), dim3(512), 0, stream>>>(keys, sidx);
    k_cen<<<dim3(M, B), dim3(128), 0, stream>>>(y, sidx, ynorm, cen, cnorm);
    k_assign<<<dim3(N, B), dim3(128), 0, stream>>>(x, cen, xnorm, cnorm, assign, nnidx);
    k_agg<<<dim3(M / 16, B), dim3(256), 0, stream>>>(assign, x, aggws);
    k_ffn<<<dim3(M, B), dim3(128), 0, stream>>>(w1, b1, g1, bt1, w2, b2, g2, bt2, aggws, refined);
    k_final<<<dim3(N / 16, B), dim3(256), 0, stream>>>(x, aggws, nnidx, nnw, nnb, nng, nnbt, out);
}

// Round 5
// 3050.079 us; speedup vs baseline: 1.0196x; 1.0196x over previous
//
#include <hip/hip_runtime.h>
#include <float.h>
#include <math.h>
#include <stdint.h>

// Problem constants (match reference)
constexpr int B   = 8;
constexpr int C   = 96;
constexpr int N   = 3136;   // 56*56
constexpr int M   = 784;    // RATIO*N
constexpr int C4  = 384;    // 4*C
constexpr int OUT = 192;
constexpr int KD  = 16;     // K_DPC
constexpr int TK  = 5;      // TOPK

// ---------------------------------------------------------------------------
// fp32 round-to-nearest of a positive double WITH flush-to-zero of subnormal
// results (validated semantics for the reference's exp underflow).
__device__ inline uint32_t f32q_ftz(double t) {
    if (t <= 0.0) return 0u;
    float f = (float)t;              // exact RN cvt (double->float)
    if (f < 0x1p-126f) return 0u;    // subnormal result -> flush to zero
    return __float_as_uint(f);
}

// ---------------------------------------------------------------------------
// K0: per-point squared norms of y and x (both laid out (B,C,N))
__global__ __launch_bounds__(256) void k_norms(const float* __restrict__ y,
                                               const float* __restrict__ x,
                                               float* __restrict__ ynorm,
                                               float* __restrict__ xnorm) {
    int id = blockIdx.x * 256 + threadIdx.x;
    if (id >= B * N) return;
    int b = id / N, n = id % N;
    const float* yb = y + (size_t)b * C * N + n;
    const float* xb = x + (size_t)b * C * N + n;
    float sy = 0.f, sx = 0.f;
    #pragma unroll 8
    for (int c = 0; c < C; ++c) {
        float a = yb[(size_t)c * N]; sy += a * a;
        float d = xb[(size_t)c * N]; sx += d * d;
    }
    ynorm[id] = sy;
    xnorm[id] = sx;
}

// ---------------------------------------------------------------------------
// K1 (rewritten): tiled distance GEMM + threshold-filtered top-16 selection.
// Block: 128 threads, TI=32 rows (i), tiles of TJ=64 cols (j).
// Thread micro-tile: 4 rows x 4 cols (tr = t/16 in 0..7, tc = t%16 in 0..15).
// Semantics identical to validated version: d = ((ni + ynj) - 2*dot) + rel
// with dot accumulated sequentially over c; top-16 is value-multiset-based;
// mean uses the numpy pairwise tree on ascending values; FTZ exp.
constexpr int TI = 32;
constexpr int TJ = 64;

__global__ __launch_bounds__(128) void k_density(const float* __restrict__ y,
                                                 const float* __restrict__ rel,
                                                 const float* __restrict__ ynorm,
                                                 uint32_t* __restrict__ densbits,
                                                 float* __restrict__ rowmax) {
    const int b  = blockIdx.y;
    const int i0 = blockIdx.x * TI;
    const int t  = threadIdx.x;
    const int tr = t >> 4;      // 0..7
    const int tc = t & 15;      // 0..15

    __shared__ __align__(16) float yiS[C][36];      // k-major, padded
    __shared__ __align__(16) float yjS[C][68];      // k-major, padded
    __shared__ float s16[TI][17];                   // per-row sorted top-16 asc
    __shared__ float candVal[TI][64];               // per-tile candidates
    __shared__ int   candCnt[TI];

    const float* yb = y + (size_t)b * C * N;

    // stage yi panel (rows i0..i0+31, all k) — coalesced float4
    for (int e = t; e < C * (TI / 4); e += 128) {
        int k = e >> 3, r4 = (e & 7) << 2;
        float4 v = *reinterpret_cast<const float4*>(yb + (size_t)k * N + i0 + r4);
        *reinterpret_cast<float4*>(&yiS[k][r4]) = v;
    }
    // init selection state
    for (int e = t; e < TI * 16; e += 128) s16[e >> 4][e & 15] = FLT_MAX;
    if (t < TI) candCnt[t] = 0;

    // per-thread row norms (rows 4*tr .. 4*tr+3)
    float4 ni4 = *reinterpret_cast<const float4*>(ynorm + (size_t)b * N + i0 + 4 * tr);
    float ni[4] = {ni4.x, ni4.y, ni4.z, ni4.w};
    float rmax[4] = {-FLT_MAX, -FLT_MAX, -FLT_MAX, -FLT_MAX};

    __syncthreads();

    for (int j0 = 0; j0 < N; j0 += TJ) {
        // stage yj panel (cols j0..j0+63, all k) — coalesced float4
        for (int e = t; e < C * (TJ / 4); e += 128) {
            int k = e >> 4, c4 = (e & 15) << 2;
            float4 v = *reinterpret_cast<const float4*>(yb + (size_t)k * N + j0 + c4);
            *reinterpret_cast<float4*>(&yjS[k][c4]) = v;
        }
        __syncthreads();

        // register-tiled dot products: acc[a][c] over k (sequential order)
        float acc[4][4] = {};
        #pragma unroll 4
        for (int k = 0; k < C; ++k) {
            float4 ra4 = *reinterpret_cast<const float4*>(&yiS[k][4 * tr]);
            float4 cb4 = *reinterpret_cast<const float4*>(&yjS[k][4 * tc]);
            float ra[4] = {ra4.x, ra4.y, ra4.z, ra4.w};
            float cb[4] = {cb4.x, cb4.y, cb4.z, cb4.w};
            #pragma unroll
            for (int a = 0; a < 4; ++a)
                #pragma unroll
                for (int c2 = 0; c2 < 4; ++c2)
                    acc[a][c2] += ra[a] * cb[c2];
        }

        // epilogue: d values, rowmax, threshold filter -> candidate append
        float4 ynj4 = *reinterpret_cast<const float4*>(ynorm + (size_t)b * N + j0 + 4 * tc);
        float ynj[4] = {ynj4.x, ynj4.y, ynj4.z, ynj4.w};
        #pragma unroll
        for (int a = 0; a < 4; ++a) {
            int row = 4 * tr + a;
            float thr = s16[row][15];
            float4 rel4 = *reinterpret_cast<const float4*>(
                rel + (size_t)(i0 + row) * N + j0 + 4 * tc);
            float rl[4] = {rel4.x, rel4.y, rel4.z, rel4.w};
            #pragma unroll
            for (int c2 = 0; c2 < 4; ++c2) {
                float d = ni[a] + ynj[c2] - 2.f * acc[a][c2] + rl[c2];
                rmax[a] = fmaxf(rmax[a], d);
                if (d < thr) {
                    int p = atomicAdd(&candCnt[row], 1);
                    candVal[row][p] = d;
                }
            }
        }
        __syncthreads();

        // sorted insertion of candidates (one thread per row; value-based)
        if (t < TI) {
            int r = t;
            int cnt = candCnt[r];
            for (int q = 0; q < cnt; ++q) {
                float v = candVal[r][q];
                if (v < s16[r][15]) {
                    int pos = 15;
                    while (pos > 0 && s16[r][pos - 1] > v) {
                        s16[r][pos] = s16[r][pos - 1];
                        --pos;
                    }
                    s16[r][pos] = v;
                }
            }
            candCnt[r] = 0;
        }
        __syncthreads();
    }

    // rowmax merge via candVal scratch (all tiles done)
    float* maxbuf = &candVal[0][0];
    #pragma unroll
    for (int a = 0; a < 4; ++a) maxbuf[t * 4 + a] = rmax[a];
    __syncthreads();

    if (t < TI) {
        int r = t;
        int trr = r >> 2, aa = r & 3;
        float mx = -FLT_MAX;
        #pragma unroll
        for (int tcc = 0; tcc < 16; ++tcc)
            mx = fmaxf(mx, maxbuf[((trr << 4) + tcc) * 4 + aa]);
        rowmax[b * N + i0 + r] = mx;

        // numpy pairwise fp32 sum of the 16 ascending values
        float r8[8];
        #pragma unroll
        for (int j2 = 0; j2 < 8; ++j2) r8[j2] = s16[r][j2] + s16[r][8 + j2];
        float s = ((r8[0] + r8[1]) + (r8[2] + r8[3]))
                + ((r8[4] + r8[5]) + (r8[6] + r8[7]));
        float mean = s * (1.0f / 16.0f);
        densbits[b * N + i0 + r] = f32q_ftz(exp(-(double)mean));
    }
}

// ---------------------------------------------------------------------------
// K2: per-batch global max of d (fp32)
__global__ __launch_bounds__(256) void k_dmax(const float* __restrict__ rowmax,
                                              float* __restrict__ dmax) {
    int b = blockIdx.x, t = threadIdx.x;
    __shared__ float rv[256];
    float lm = -FLT_MAX;
    for (int j = t; j < N; j += 256) lm = fmaxf(lm, rowmax[b * N + j]);
    rv[t] = lm;
    __syncthreads();
    for (int s = 128; s > 0; s >>= 1) {
        if (t < s) rv[t] = fmaxf(rv[t], rv[t + s]);
        __syncthreads();
    }
    if (t == 0) dmax[b] = rv[0];
}

// ---------------------------------------------------------------------------
// K3: dist_peak = min over j with dens[j] > dens[i] of d[i,j] (else dmax);
// score = fp32(dist_peak * density) emulated exactly; packed rank key.
// Zero-density rows short-circuit: score is exactly +0.
__global__ __launch_bounds__(256) void k_score(const float* __restrict__ y,
                                               const float* __restrict__ rel,
                                               const float* __restrict__ ynorm,
                                               const uint32_t* __restrict__ densbits,
                                               const float* __restrict__ dmax,
                                               unsigned long long* __restrict__ keys) {
    const int i = blockIdx.x;
    const int b = blockIdx.y;
    const int t = threadIdx.x;

    const uint32_t bi = densbits[b * N + i];
    if (bi == 0u) {   // score == +0.0 exactly; key = (0, ~idx)
        if (t == 0) keys[b * N + i] =
            (unsigned long long)(0xFFFFFFFFu - (uint32_t)i);
        return;
    }

    __shared__ float yi[C];
    __shared__ float rv[256];

    const float* yb = y + (size_t)b * C * N;
    if (t < C) yi[t] = yb[(size_t)t * N + i];
    __syncthreads();

    const float ni = ynorm[b * N + i];
    float mn = FLT_MAX;
    for (int j = t; j < N; j += 256) {
        if (densbits[b * N + j] > bi) {
            const float* p = yb + j;
            float dot = 0.f;
            #pragma unroll 8
            for (int c = 0; c < C; ++c) dot += yi[c] * p[(size_t)c * N];
            float d = ni + ynorm[b * N + j] - 2.f * dot + rel[(size_t)i * N + j];
            mn = fminf(mn, d);
        }
    }
    rv[t] = mn;
    __syncthreads();
    for (int s = 128; s > 0; s >>= 1) {
        if (t < s) rv[t] = fminf(rv[t], rv[t + s]);
        __syncthreads();
    }
    if (t == 0) {
        float dp = fminf(rv[0], dmax[b]);
        // exact single-rounded fp32 product (both factors are fp32 values)
        double p = (double)dp * (double)__uint_as_float(bi);
        float sf = (float)p;
        uint32_t sb = (sf < 0x1p-126f) ? 0u : __float_as_uint(sf);
        keys[b * N + i] = ((unsigned long long)sb << 32)
                        | (unsigned long long)(0xFFFFFFFFu - (uint32_t)i);
    }
}

// ---------------------------------------------------------------------------
// K4: per-batch bitonic sort of packed keys, descending -> top M indices.
__global__ __launch_bounds__(512) void k_topm(const unsigned long long* __restrict__ keys,
                                              int* __restrict__ sidx) {
    constexpr int SZ = 4096;
    int b = blockIdx.x, t = threadIdx.x;
    __shared__ unsigned long long ks[SZ];
    for (int i = t; i < SZ; i += 512) ks[i] = (i < N) ? keys[b * N + i] : 0ull;
    __syncthreads();
    for (int k = 2; k <= SZ; k <<= 1) {
        for (int j = k >> 1; j > 0; j >>= 1) {
            for (int i = t; i < SZ; i += 512) {
                int ixj = i ^ j;
                if (ixj > i) {
                    bool up = ((i & k) == 0);
                    unsigned long long a = ks[i], c2 = ks[ixj];
                    bool doSwap = up ? (a < c2) : (a > c2);  // descending
                    if (doSwap) { ks[i] = c2; ks[ixj] = a; }
                }
            }
            __syncthreads();
        }
    }
    for (int m = t; m < M; m += 512)
        sidx[b * M + m] = (int)(0xFFFFFFFFu - (uint32_t)(ks[m] & 0xFFFFFFFFull));
}

// ---------------------------------------------------------------------------
// K5: gather centers cen[b,m,c] = y[b,c,sidx] and their norms
__global__ __launch_bounds__(128) void k_cen(const float* __restrict__ y,
                                             const int* __restrict__ sidx,
                                             const float* __restrict__ ynorm,
                                             float* __restrict__ cen,
                                             float* __restrict__ cnorm) {
    int m = blockIdx.x, b = blockIdx.y, t = threadIdx.x;
    int j = sidx[b * M + m];
    if (t < C) cen[((size_t)b * M + m) * C + t] = y[((size_t)b * C + t) * N + j];
    if (t == 0) cnorm[b * M + m] = ynorm[b * N + j];
}

// ---------------------------------------------------------------------------
// K6: assignment softmax row + top-5 center indices per point (logit-ranked)
__global__ __launch_bounds__(128) void k_assign(const float* __restrict__ x,
                                                const float* __restrict__ cen,
                                                const float* __restrict__ xnorm,
                                                const float* __restrict__ cnorm,
                                                float* __restrict__ assign,
                                                int* __restrict__ nnidx) {
    const int i = blockIdx.x;
    const int b = blockIdx.y;
    const int t = threadIdx.x;
    __shared__ float xi[C];
    __shared__ float S[M];   // logits
    __shared__ float rv[128];
    __shared__ int   ri[128];

    if (t < C) xi[t] = x[((size_t)b * C + t) * N + i];
    __syncthreads();

    const float xn = xnorm[b * N + i];
    for (int m = t; m < M; m += 128) {
        const float* cm = cen + ((size_t)b * M + m) * C;
        float dot = 0.f;
        #pragma unroll 8
        for (int c = 0; c < C; ++c) dot += xi[c] * cm[c];
        S[m] = -(xn + cnorm[b * M + m] - 2.f * dot);
    }
    __syncthreads();

    float lm = -FLT_MAX;
    for (int m = t; m < M; m += 128) lm = fmaxf(lm, S[m]);
    rv[t] = lm;
    __syncthreads();
    for (int s = 64; s > 0; s >>= 1) {
        if (t < s) rv[t] = fmaxf(rv[t], rv[t + s]);
        __syncthreads();
    }
    float smax = rv[0];
    __syncthreads();

    float lsum = 0.f;
    for (int m = t; m < M; m += 128) lsum += expf(S[m] - smax);
    rv[t] = lsum;
    __syncthreads();
    for (int s = 64; s > 0; s >>= 1) {
        if (t < s) rv[t] += rv[t + s];
        __syncthreads();
    }
    float inv = 1.f / rv[0];
    __syncthreads();

    float* arow = assign + ((size_t)b * N + i) * M;
    for (int m = t; m < M; m += 128) arow[m] = expf(S[m] - smax) * inv;

    for (int r = 0; r < TK; ++r) {
        float lv = -FLT_MAX; int li = M;
        for (int m = t; m < M; m += 128) {
            float v = S[m];
            if (v > lv || (v == lv && m < li)) { lv = v; li = m; }
        }
        rv[t] = lv; ri[t] = li;
        __syncthreads();
        for (int s = 64; s > 0; s >>= 1) {
            if (t < s) {
                if (rv[t + s] > rv[t] || (rv[t + s] == rv[t] && ri[t + s] < ri[t])) {
                    rv[t] = rv[t + s]; ri[t] = ri[t + s];
                }
            }
            __syncthreads();
        }
        if (t == 0) {
            nnidx[((size_t)b * N + i) * TK + r] = ri[0];
            S[ri[0]] = -FLT_MAX;
        }
        __syncthreads();
    }
}

// ---------------------------------------------------------------------------
// K7: agg[b,m,c] = (sum_n assign[n,m] * x[c,n]) / (mass_m + 1e-6)
__global__ __launch_bounds__(256) void k_agg(const float* __restrict__ assign,
                                             const float* __restrict__ x,
                                             float* __restrict__ aggws) {
    const int b = blockIdx.y;
    const int m0 = blockIdx.x * 16;
    const int t = threadIdx.x;
    __shared__ float As[64][16];
    __shared__ float Xs[96][65];
    __shared__ float minv[16];

    float acc[6] = {0.f, 0.f, 0.f, 0.f, 0.f, 0.f};
    float massacc = 0.f;

    for (int n0 = 0; n0 < N; n0 += 64) {
        for (int e = t; e < 64 * 16; e += 256) {
            int nn = e >> 4, mm = e & 15;
            As[nn][mm] = assign[((size_t)b * N + n0 + nn) * M + m0 + mm];
        }
        for (int e = t; e < 96 * 64; e += 256) {
            int c = e >> 6, nn = e & 63;
            Xs[c][nn] = x[((size_t)b * C + c) * N + n0 + nn];
        }
        __syncthreads();
        if (t < 16) {
            #pragma unroll
            for (int nn = 0; nn < 64; ++nn) massacc += As[nn][t];
        }
        #pragma unroll
        for (int u = 0; u < 6; ++u) {
            int e = t + u * 256;
            int mm = e & 15, c = e >> 4;
            float a = acc[u];
            #pragma unroll 8
            for (int nn = 0; nn < 64; ++nn) a += As[nn][mm] * Xs[c][nn];
            acc[u] = a;
        }
        __syncthreads();
    }
    if (t < 16) minv[t] = 1.f / (massacc + 1e-6f);
    __syncthreads();
    #pragma unroll
    for (int u = 0; u < 6; ++u) {
        int e = t + u * 256;
        int mm = e & 15, c = e >> 4;
        aggws[((size_t)b * M + m0 + mm) * C + c] = acc[u] * minv[mm];
    }
}

// ---------------------------------------------------------------------------
// K8: per-center FFN with residual; writes updated agg (ws) and `refined`
__global__ __launch_bounds__(128) void k_ffn(const float* __restrict__ w1,
                                             const float* __restrict__ b1,
                                             const float* __restrict__ g1,
                                             const float* __restrict__ bt1,
                                             const float* __restrict__ w2,
                                             const float* __restrict__ b2,
                                             const float* __restrict__ g2,
                                             const float* __restrict__ bt2,
                                             float* __restrict__ aggws,
                                             float* __restrict__ refined) {
    const int m = blockIdx.x;
    const int b = blockIdx.y;
    const int t = threadIdx.x;
    __shared__ float ar[C];
    __shared__ float hd[C4];

    if (t < C) ar[t] = aggws[((size_t)b * M + m) * C + t];
    __syncthreads();

    for (int o = t; o < C4; o += 128) {
        const float* w = w1 + (size_t)o * C;
        float h = b1[o];
        #pragma unroll 8
        for (int c = 0; c < C; ++c) h += w[c] * ar[c];
        h = h * g1[o] + bt1[o];
        hd[o] = fmaxf(h, 0.f);
    }
    __syncthreads();

    if (t < C) {
        const float* w = w2 + (size_t)t * C4;
        float f = b2[t];
        #pragma unroll 8
        for (int o = 0; o < C4; ++o) f += w[o] * hd[o];
        float v = ar[t] + (f * g2[t] + bt2[t]);
        aggws[((size_t)b * M + m) * C + t] = v;
        refined[((size_t)b * C + t) * M + m] = v;
    }
}

// ---------------------------------------------------------------------------
// K9: rel = max over top-5 agg rows - xf; interleaved xcat;
// out = relu((nn_w @ xcat + nn_b) * g + bt), stored (B, OUT, N)
__global__ __launch_bounds__(256) void k_final(const float* __restrict__ x,
                                               const float* __restrict__ aggws,
                                               const int* __restrict__ nnidx,
                                               const float* __restrict__ nnw,
                                               const float* __restrict__ nnb,
                                               const float* __restrict__ nng,
                                               const float* __restrict__ nnbt,
                                               float* __restrict__ out) {
    const int b = blockIdx.y;
    const int n0 = blockIdx.x * 16;
    const int t = threadIdx.x;
    __shared__ float xc[16][193];
    __shared__ int nid[16 * TK];

    if (t < 16 * TK) nid[t] = nnidx[((size_t)b * N + n0) * TK + t];
    __syncthreads();

    for (int e = t; e < C * 16; e += 256) {
        int c = e >> 4, r = e & 15;
        float xv = x[((size_t)b * C + c) * N + n0 + r];
        float mx = -FLT_MAX;
        #pragma unroll
        for (int k = 0; k < TK; ++k) {
            int j = nid[r * TK + k];
            mx = fmaxf(mx, aggws[((size_t)b * M + j) * C + c]);
        }
        xc[r][2 * c]     = xv;
        xc[r][2 * c + 1] = mx - xv;
    }
    __syncthreads();

    const int r = t & 15;
    const int og = t >> 4;
    #pragma unroll
    for (int oo = 0; oo < 12; ++oo) {
        int o = og + (oo << 4);
        const float* w = nnw + (size_t)o * (2 * C);
        float a = nnb[o];
        #pragma unroll 8
        for (int cc = 0; cc < 2 * C; ++cc) a += w[cc] * xc[r][cc];
        a = a * nng[o] + nnbt[o];
        out[((size_t)b * OUT + o) * N + n0 + r] = fmaxf(a, 0.f);
    }
}

// ---------------------------------------------------------------------------
extern "C" void kernel_launch(void* const* d_in, const int* in_sizes, int n_in,
                              void* d_out, int out_size, void* d_ws, size_t ws_size,
                              hipStream_t stream) {
    const float* x    = (const float*)d_in[0];
    const float* rel  = (const float*)d_in[1];
    const float* y    = (const float*)d_in[2];
    const float* w1   = (const float*)d_in[3];
    const float* b1   = (const float*)d_in[4];
    const float* g1   = (const float*)d_in[5];
    const float* bt1  = (const float*)d_in[6];
    const float* w2   = (const float*)d_in[7];
    const float* b2   = (const float*)d_in[8];
    const float* g2   = (const float*)d_in[9];
    const float* bt2  = (const float*)d_in[10];
    const float* nnw  = (const float*)d_in[11];
    const float* nnb  = (const float*)d_in[12];
    const float* nng  = (const float*)d_in[13];
    const float* nnbt = (const float*)d_in[14];

    float* out     = (float*)d_out;
    float* refined = out + (size_t)B * OUT * N;

    char* w = (char*)d_ws;
    auto alloc = [&](size_t nbytes) -> void* {
        void* p = (void*)w;
        w += (nbytes + 255) & ~(size_t)255;
        return p;
    };
    float*    ynorm    = (float*)   alloc((size_t)B * N * 4);
    float*    xnorm    = (float*)   alloc((size_t)B * N * 4);
    uint32_t* densbits = (uint32_t*)alloc((size_t)B * N * 4);
    float*    rowmax   = (float*)   alloc((size_t)B * N * 4);
    float*    dmaxv    = (float*)   alloc((size_t)B * 4);
    unsigned long long* keys = (unsigned long long*)alloc((size_t)B * N * 8);
    int*      sidx     = (int*)     alloc((size_t)B * M * 4);
    float*    cnorm    = (float*)   alloc((size_t)B * M * 4);
    float*    cen      = (float*)   alloc((size_t)B * M * C * 4);
    float*    aggws    = (float*)   alloc((size_t)B * M * C * 4);
    int*      nnidx    = (int*)     alloc((size_t)B * N * TK * 4);
    float*    assign   = (float*)   alloc((size_t)B * N * M * 4);

    k_norms<<<dim3((B * N + 255) / 256), dim3(256), 0, stream>>>(y, x, ynorm, xnorm);
    k_density<<<dim3(N / TI, B), dim3(128), 0, stream>>>(y, rel, ynorm, densbits, rowmax);
    k_dmax<<<dim3(B), dim3(256), 0, stream>>>(rowmax, dmaxv);
    k_score<<<dim3(N, B), dim3(256), 0, stream>>>(y, rel, ynorm, densbits, dmaxv, keys);
    k_topm<<<dim3(B), dim3(512), 0, stream>>>(keys, sidx);
    k_cen<<<dim3(M, B), dim3(128), 0, stream>>>(y, sidx, ynorm, cen, cnorm);
    k_assign<<<dim3(N, B), dim3(128), 0, stream>>>(x, cen, xnorm, cnorm, assign, nnidx);
    k_agg<<<dim3(M / 16, B), dim3(256), 0, stream>>>(assign, x, aggws);
    k_ffn<<<dim3(M, B), dim3(128), 0, stream>>>(w1, b1, g1, bt1, w2, b2, g2, bt2, aggws, refined);
    k_final<<<dim3(N / 16, B), dim3(256), 0, stream>>>(x, aggws, nnidx, nnw, nnb, nng, nnbt, out);
}